// Round 6
// baseline (576.557 us; speedup 1.0000x reference)
//
#include <hip/hip_runtime.h>
#include <hip/hip_bf16.h>
#include <math.h>

typedef __attribute__((ext_vector_type(8))) short short8;
typedef __attribute__((ext_vector_type(4))) float floatx4;
typedef unsigned short u16;
typedef unsigned int u32;

// ---------- bf16 helpers ----------
__device__ __forceinline__ float b2f(u16 u) {
  union { u32 i; float f; } v; v.i = ((u32)u) << 16; return v.f;
}
__device__ __forceinline__ u16 f2b(float f) {
  union { float f; u32 i; } v; v.f = f;
  u32 i = v.i;
  return (u16)((i + 0x7fffu + ((i >> 16) & 1u)) >> 16);  // RNE
}

// ---------- async global->LDS (16B/lane) ----------
#define GLD16(gp, lp)                                                          \
  __builtin_amdgcn_global_load_lds(                                            \
      (__attribute__((address_space(1))) u32*)(gp),                            \
      (__attribute__((address_space(3))) u32*)(lp), 16, 0, 0)

// ---------- constants ----------
#define T_TOK 4096
#define DDIM 1024
#define FDIM 2048
#define NEXP 8
#define CAP_ROWS 9216   // 8192 assignments + 8*128 padding
#define CAP_MBLK 72     // CAP_ROWS/128

// ---------- fallback: ws too small -> sentinel 1e6 (distinguishable) ----------
__global__ void fallback_k(float* out, int n) {
  int i = blockIdx.x * 256 + threadIdx.x;
  if (i < n) out[i] = 1.0e6f;
}

// ---------- init ----------
__global__ void init_k(int* counts, int* rowtok) {
  int i = blockIdx.x * 256 + threadIdx.x;
  if (i < CAP_ROWS) rowtok[i] = -1;
  if (i < NEXP) counts[i] = 0;
}

// ---------- convert x f32 -> bf16 ----------
__global__ void cvt_k(const float* __restrict__ x, u16* __restrict__ xb) {
  int i = (blockIdx.x * 256 + threadIdx.x) * 4;
  float4 v = *(const float4*)(x + i);
  union { u16 h[4]; uint2 u; } o;
  o.h[0] = f2b(v.x); o.h[1] = f2b(v.y); o.h[2] = f2b(v.z); o.h[3] = f2b(v.w);
  *(uint2*)(xb + i) = o.u;
}

// ---------- router: one wave per token, FULL f32 (selection must match ref) ----------
__global__ __launch_bounds__(256) void router_k(const float* __restrict__ x,
                                                const float* __restrict__ Wg,
                                                int* topi, float* topw, int* counts) {
  int wave = threadIdx.x >> 6, lane = threadIdx.x & 63;
  int t = blockIdx.x * 4 + wave;
  const float* xr = x + (size_t)t * DDIM;
  float p[NEXP];
#pragma unroll
  for (int e = 0; e < NEXP; e++) p[e] = 0.f;
#pragma unroll
  for (int i = 0; i < DDIM / 64; i++) {
    int d = lane + i * 64;
    float xv = xr[d];
    float4 w0 = *(const float4*)(Wg + (size_t)d * NEXP);
    float4 w1 = *(const float4*)(Wg + (size_t)d * NEXP + 4);
    p[0] += xv * w0.x; p[1] += xv * w0.y; p[2] += xv * w0.z; p[3] += xv * w0.w;
    p[4] += xv * w1.x; p[5] += xv * w1.y; p[6] += xv * w1.z; p[7] += xv * w1.w;
  }
#pragma unroll
  for (int off = 32; off > 0; off >>= 1)
#pragma unroll
    for (int e = 0; e < NEXP; e++) p[e] += __shfl_down(p[e], off);
  if (lane == 0) {
    int i0 = 0; float l0 = p[0];
    for (int e = 1; e < NEXP; e++) if (p[e] > l0) { l0 = p[e]; i0 = e; }
    int i1 = (i0 == 0) ? 1 : 0; float l1 = p[i1];  // defensive: i1 always valid
    for (int e = 0; e < NEXP; e++) if (e != i0 && p[e] > l1) { l1 = p[e]; i1 = e; }
    // renormalized top-2 of softmax == softmax over the two logits
    float e1 = expf(l1 - l0);
    float s = 1.0f + e1;
    topi[t * 2] = i0; topi[t * 2 + 1] = i1;
    topw[t * 2] = 1.0f / s; topw[t * 2 + 1] = e1 / s;
    atomicAdd(&counts[i0], 1); atomicAdd(&counts[i1], 1);
  }
}

// ---------- scan: 128-aligned per-expert offsets ----------
__global__ void scan_k(const int* counts, int* cursor, int* blk_e, int* nrows) {
  if (threadIdx.x == 0 && blockIdx.x == 0) {
    int off = 0;
    for (int e = 0; e < NEXP; e++) {
      cursor[e] = off;
      int c = counts[e]; if (c < 0) c = 0; if (c > 8192) c = 8192;
      int nb = (c + 127) >> 7;
      for (int b = 0; b < nb; b++) {
        int bi = (off >> 7) + b;
        if (bi < 128) blk_e[bi] = e;
      }
      off += nb << 7;
    }
    if (off > CAP_ROWS) off = CAP_ROWS;
    *nrows = off;
  }
}

// ---------- assign: token-slot -> sorted row; per-row weight ----------
__global__ void assign_k(const int* topi, const float* topw, int* cursor,
                         int* rowtok, float* rww) {
  int i = blockIdx.x * 256 + threadIdx.x;  // i < 8192
  int e = topi[i]; if (e < 0) e = 0; if (e >= NEXP) e = NEXP - 1;
  int r = atomicAdd(&cursor[e], 1);
  if (r < 0) r = 0; if (r >= CAP_ROWS) r = CAP_ROWS - 1;
  rowtok[r] = i >> 1;
  rww[r] = topw[i];
}

// ---------- transpose+convert: f32 [R][C] -> bf16 [C][R], batched ----------
__global__ void transpose_cvt_k(const float* __restrict__ src, u16* __restrict__ dst,
                                int R, int C) {
  __shared__ float tile[32][33];
  size_t base = (size_t)blockIdx.z * R * C;
  int c0 = blockIdx.x * 32, r0 = blockIdx.y * 32;
#pragma unroll
  for (int i = 0; i < 4; i++)
    tile[threadIdx.y + i * 8][threadIdx.x] =
        src[base + (size_t)(r0 + threadIdx.y + i * 8) * C + c0 + threadIdx.x];
  __syncthreads();
#pragma unroll
  for (int i = 0; i < 4; i++)
    dst[base + (size_t)(c0 + threadIdx.y + i * 8) * R + r0 + threadIdx.x] =
        f2b(tile[threadIdx.x][threadIdx.y + i * 8]);
}

// ---------- 128x128 bf16 MFMA GEMM, B pre-transposed [N][K] ----------
// MODE 0: gelu -> bf16 store to C16
// MODE 1: f32 store to Cf
// MODE 2: atomic f32: Cf[rowtok[row]*N+col] += rww[row]*v  (skip rowtok<0)
// gatherA: A-row indirection for staging (fused token gather), -1 -> 0.
template <int MODE>
__global__ __launch_bounds__(256) void gemm_bt(
    const u16* __restrict__ A, const u16* __restrict__ Bt,
    u16* __restrict__ C16, float* __restrict__ Cf,
    int N, int K, const int* __restrict__ blk_e, const int* __restrict__ nrows,
    size_t bstride, const int* __restrict__ gatherA,
    const int* __restrict__ rowtok, const float* __restrict__ rww) {
  const int m0 = blockIdx.y * 128, n0 = blockIdx.x * 128;
  if (nrows && m0 >= *nrows) return;
  if (blk_e) Bt += (size_t)blk_e[blockIdx.y] * bstride;

  __shared__ u16 As[128 * 32];
  __shared__ u16 Bs[128 * 32];
  const int tid = threadIdx.x, wave = tid >> 6, lane = tid & 63;
  // staging: wave w covers rows [w*16, w*16+16), 16B/lane; LDS = base + lane*16
  const int srow = wave * 16 + (lane >> 2);
  const int scol = (lane & 3) * 8;
  int r0 = m0 + srow, r1 = r0 + 64;
  if (gatherA) {
    int t = gatherA[r0]; r0 = (t < 0 || t >= T_TOK) ? 0 : t;
    t = gatherA[r1];     r1 = (t < 0 || t >= T_TOK) ? 0 : t;
  }
  const u16* Ag0 = A + (size_t)r0 * K + scol;
  const u16* Ag1 = A + (size_t)r1 * K + scol;
  const u16* Bg = Bt + (size_t)(n0 + srow) * K + scol;
  u16* Al = As + srow * 32 + scol;
  u16* Bl = Bs + srow * 32 + scol;

  const int wr = (wave >> 1) * 64, wc = (wave & 1) * 64;
  const int fr = lane & 15, fk = (lane >> 4) * 8;

  floatx4 acc[4][4];
#pragma unroll
  for (int mi = 0; mi < 4; mi++)
#pragma unroll
    for (int ni = 0; ni < 4; ni++) acc[mi][ni] = (floatx4){0.f, 0.f, 0.f, 0.f};

  for (int k0 = 0; k0 < K; k0 += 32) {
    __syncthreads();
    GLD16(Ag0 + k0, Al);
    GLD16(Ag1 + k0, Al + 64 * 32);
    GLD16(Bg + k0, Bl);
    GLD16(Bg + k0 + (size_t)64 * K, Bl + 64 * 32);
    __syncthreads();
    short8 aF[4], bF[4];
#pragma unroll
    for (int mi = 0; mi < 4; mi++)
      aF[mi] = *(const short8*)(As + (wr + mi * 16 + fr) * 32 + fk);
#pragma unroll
    for (int ni = 0; ni < 4; ni++)
      bF[ni] = *(const short8*)(Bs + (wc + ni * 16 + fr) * 32 + fk);
#pragma unroll
    for (int mi = 0; mi < 4; mi++)
#pragma unroll
      for (int ni = 0; ni < 4; ni++)
        acc[mi][ni] = __builtin_amdgcn_mfma_f32_16x16x32_bf16(aF[mi], bF[ni],
                                                              acc[mi][ni], 0, 0, 0);
  }
  // epilogue: C/D layout col=lane&15, row=(lane>>4)*4+reg
#pragma unroll
  for (int mi = 0; mi < 4; mi++)
#pragma unroll
    for (int r = 0; r < 4; r++) {
      int row = m0 + wr + mi * 16 + (lane >> 4) * 4 + r;
      int tok = 0; float w = 0.f;
      if (MODE == 2) {
        tok = rowtok[row];
        if (tok >= 0) w = rww[row];
      }
#pragma unroll
      for (int ni = 0; ni < 4; ni++) {
        int col = n0 + wc + ni * 16 + fr;
        float v = acc[mi][ni][r];
        if (MODE == 0) {
          v = 0.5f * v * (1.0f + erff(v * 0.70710678118654752f));
          C16[(size_t)row * N + col] = f2b(v);
        } else if (MODE == 1) {
          Cf[(size_t)row * N + col] = v;
        } else {
          if (tok >= 0) atomicAdd(Cf + (size_t)tok * N + col, w * v);
        }
      }
    }
}

extern "C" void kernel_launch(void* const* d_in, const int* in_sizes, int n_in,
                              void* d_out, int out_size, void* d_ws, size_t ws_size,
                              hipStream_t stream) {
  const float* x  = (const float*)d_in[0];
  const float* Wg = (const float*)d_in[1];
  const float* Wu = (const float*)d_in[2];
  const float* Wd = (const float*)d_in[3];
  const float* W1 = (const float*)d_in[4];
  const float* W2 = (const float*)d_in[5];
  float* out = (float*)d_out;

  // ---- workspace layout (phase-reused; ~102 MB) ----
  char* ws = (char*)d_ws;
  size_t off = 0;
  auto alloc = [&](size_t b) -> void* {
    void* p = ws + off; off += (b + 255) & ~(size_t)255; return p;
  };
  int*   counts = (int*)alloc(NEXP * 4);
  int*   cursor = (int*)alloc(NEXP * 4);
  int*   nrows  = (int*)alloc(4);
  int*   blk_e  = (int*)alloc(128 * 4);
  int*   topi   = (int*)alloc(T_TOK * 2 * 4);
  float* topw   = (float*)alloc(T_TOK * 2 * 4);
  int*   rowtok = (int*)alloc(CAP_ROWS * 4);
  float* rww    = (float*)alloc(CAP_ROWS * 4);
  u16*   Xb     = (u16*)alloc((size_t)T_TOK * DDIM * 2);            // 8.4 MB
  u16*   WtA    = (u16*)alloc((size_t)DDIM * FDIM * 2);             // 4.2 MB: W1t then W2t
  u16*   WtB    = (u16*)alloc((size_t)NEXP * FDIM * DDIM * 2);      // 33.6 MB: Wut then Wdt
  u16*   H1g    = (u16*)alloc((size_t)T_TOK * FDIM * 2);            // 16.8 MB
  u16*   Hrg    = (u16*)alloc((size_t)CAP_ROWS * FDIM * 2);         // 37.7 MB
  (void)n_in; (void)in_sizes; (void)out_size;

  // ---- ws guard: sentinel output so this failure mode is identifiable ----
  if (ws_size < off) {
    fallback_k<<<(T_TOK * DDIM + 255) / 256, 256, 0, stream>>>(out, T_TOK * DDIM);
    return;
  }

  u16* W1t = WtA;  u16* Wut = WtB;   // phase-1 views
  u16* W2t = WtA;  u16* Wdt = WtB;   // phase-2/3 views

  dim3 tb(32, 8);
  // ---- routing (f32 logits: selection must match reference bit-closely) ----
  init_k<<<(CAP_ROWS + 255) / 256, 256, 0, stream>>>(counts, rowtok);
  cvt_k<<<T_TOK * DDIM / 1024, 256, 0, stream>>>(x, Xb);
  router_k<<<T_TOK / 4, 256, 0, stream>>>(x, Wg, topi, topw, counts);
  scan_k<<<1, 64, 0, stream>>>(counts, cursor, blk_e, nrows);
  assign_k<<<T_TOK * 2 / 256, 256, 0, stream>>>(topi, topw, cursor, rowtok, rww);
  // ---- phase 1: up-projections ----
  transpose_cvt_k<<<dim3(FDIM / 32, DDIM / 32, 1), tb, 0, stream>>>(W1, W1t, DDIM, FDIM);
  transpose_cvt_k<<<dim3(FDIM / 32, DDIM / 32, NEXP), tb, 0, stream>>>(Wu, Wut, DDIM, FDIM);
  // H1g = gelu(x @ W1)   [4096,2048] bf16
  gemm_bt<0><<<dim3(FDIM / 128, T_TOK / 128), 256, 0, stream>>>(
      Xb, W1t, H1g, nullptr, FDIM, DDIM, nullptr, nullptr, 0, nullptr, nullptr, nullptr);
  // Hrg = gelu(gather(x) @ Wu[e])  [<=9216,2048] bf16 (fused token gather)
  gemm_bt<0><<<dim3(FDIM / 128, CAP_MBLK), 256, 0, stream>>>(
      Xb, Wut, Hrg, nullptr, FDIM, DDIM, blk_e, nrows, (size_t)FDIM * DDIM,
      rowtok, nullptr, nullptr);
  // ---- phase 2: shared down -> out (f32, full overwrite) ----
  transpose_cvt_k<<<dim3(DDIM / 32, FDIM / 32, 1), tb, 0, stream>>>(W2, W2t, FDIM, DDIM);
  gemm_bt<1><<<dim3(DDIM / 128, T_TOK / 128), 256, 0, stream>>>(
      H1g, W2t, nullptr, out, DDIM, FDIM, nullptr, nullptr, 0, nullptr, nullptr, nullptr);
  // ---- phase 3: routed down, combine fused via atomicAdd into out ----
  transpose_cvt_k<<<dim3(DDIM / 32, FDIM / 32, NEXP), tb, 0, stream>>>(Wd, Wdt, FDIM, DDIM);
  gemm_bt<2><<<dim3(DDIM / 128, CAP_MBLK), 256, 0, stream>>>(
      Hrg, Wdt, nullptr, out, DDIM, FDIM, blk_e, nrows, (size_t)DDIM * FDIM,
      nullptr, rowtok, rww);
}

// Round 7
// 572.891 us; speedup vs baseline: 1.0064x; 1.0064x over previous
//
#include <hip/hip_runtime.h>
#include <hip/hip_bf16.h>
#include <math.h>

typedef __attribute__((ext_vector_type(8))) short short8;
typedef __attribute__((ext_vector_type(4))) float floatx4;
typedef unsigned short u16;
typedef unsigned int u32;

// ---------- bf16 helpers ----------
__device__ __forceinline__ float b2f(u16 u) {
  union { u32 i; float f; } v; v.i = ((u32)u) << 16; return v.f;
}
__device__ __forceinline__ u16 f2b(float f) {
  union { float f; u32 i; } v; v.f = f;
  u32 i = v.i;
  return (u16)((i + 0x7fffu + ((i >> 16) & 1u)) >> 16);  // RNE
}

// ---------- async global->LDS (16B/lane) ----------
#define GLD16(gp, lp)                                                          \
  __builtin_amdgcn_global_load_lds(                                            \
      (__attribute__((address_space(1))) u32*)(gp),                            \
      (__attribute__((address_space(3))) u32*)(lp), 16, 0, 0)

// ---------- constants ----------
#define T_TOK 4096
#define DDIM 1024
#define FDIM 2048
#define NEXP 8
#define CAP_ROWS 9216   // 8192 assignments + 8*128 padding
#define CAP_MBLK 72     // CAP_ROWS/128

// ---------- fallback: ws too small -> sentinel 1e6 (distinguishable) ----------
__global__ void fallback_k(float* out, int n) {
  int i = blockIdx.x * 256 + threadIdx.x;
  if (i < n) out[i] = 1.0e6f;
}

// ---------- init ----------
__global__ void init_k(int* counts, int* rowtok) {
  int i = blockIdx.x * 256 + threadIdx.x;
  if (i < CAP_ROWS) rowtok[i] = -1;
  if (i < NEXP) counts[i] = 0;
}

// ---------- convert x f32 -> bf16 ----------
__global__ void cvt_k(const float* __restrict__ x, u16* __restrict__ xb) {
  int i = (blockIdx.x * 256 + threadIdx.x) * 4;
  float4 v = *(const float4*)(x + i);
  union { u16 h[4]; uint2 u; } o;
  o.h[0] = f2b(v.x); o.h[1] = f2b(v.y); o.h[2] = f2b(v.z); o.h[3] = f2b(v.w);
  *(uint2*)(xb + i) = o.u;
}

// ---------- router v2: LDS-staged Wg (transposed), 16 tokens/block ----------
// Round-6 router was latency-bound (32 VGPR, serialized global Wg loads, 99us).
// Here Wg lives in LDS as [e][d] (lane float4 reads stride-16B = conflict-free);
// f32 math preserved so expert SELECTION matches the f32 reference.
__global__ __launch_bounds__(256) void router_k(const float* __restrict__ x,
                                                const float* __restrict__ Wg,
                                                int* topi, float* topw, int* counts) {
  __shared__ float wgl[NEXP * DDIM];  // 32 KB, [e][d]
  const int tid = threadIdx.x;
#pragma unroll
  for (int k = 0; k < (NEXP * DDIM) / 256; k++) {
    int i = tid + k * 256;          // coalesced flat read of Wg [d][e]
    wgl[(i & 7) * DDIM + (i >> 3)] = Wg[i];
  }
  __syncthreads();
  const int wave = tid >> 6, lane = tid & 63;
  for (int j = 0; j < 4; j++) {
    int t = blockIdx.x * 16 + wave * 4 + j;
    const float* xr = x + (size_t)t * DDIM;
    float p[NEXP];
#pragma unroll
    for (int e = 0; e < NEXP; e++) p[e] = 0.f;
#pragma unroll
    for (int i = 0; i < 4; i++) {
      int d0 = i * 256 + lane * 4;
      float4 xv = *(const float4*)(xr + d0);
#pragma unroll
      for (int e = 0; e < NEXP; e++) {
        float4 wv = *(const float4*)(wgl + e * DDIM + d0);
        p[e] += xv.x * wv.x + xv.y * wv.y + xv.z * wv.z + xv.w * wv.w;
      }
    }
#pragma unroll
    for (int off = 32; off > 0; off >>= 1)
#pragma unroll
      for (int e = 0; e < NEXP; e++) p[e] += __shfl_xor(p[e], off);
    if (lane == 0) {
      int i0 = 0; float l0 = p[0];
      for (int e = 1; e < NEXP; e++) if (p[e] > l0) { l0 = p[e]; i0 = e; }
      int i1 = (i0 == 0) ? 1 : 0; float l1 = p[i1];  // defensive: i1 always valid
      for (int e = 0; e < NEXP; e++) if (e != i0 && p[e] > l1) { l1 = p[e]; i1 = e; }
      // renormalized top-2 of softmax == softmax over the two logits
      float e1 = expf(l1 - l0);
      float s = 1.0f + e1;
      topi[t * 2] = i0; topi[t * 2 + 1] = i1;
      topw[t * 2] = 1.0f / s; topw[t * 2 + 1] = e1 / s;
      atomicAdd(&counts[i0], 1); atomicAdd(&counts[i1], 1);
    }
  }
}

// ---------- scan v2: serial 8-expert prefix, parallel blk_e fill ----------
__global__ void scan_k(const int* counts, int* cursor, int* blk_e, int* nrows) {
  __shared__ int soff[NEXP + 1];
  const int tid = threadIdx.x;  // 128 threads
  if (tid == 0) {
    int off = 0;
    for (int e = 0; e < NEXP; e++) {
      soff[e] = off;
      int c = counts[e]; if (c < 0) c = 0; if (c > 8192) c = 8192;
      off += ((c + 127) >> 7) << 7;
    }
    if (off > CAP_ROWS) off = CAP_ROWS;
    soff[NEXP] = off;
    *nrows = off;
  }
  __syncthreads();
  if (tid < NEXP) cursor[tid] = soff[tid];
  if (tid < 128) {
    int r = tid << 7;
    int e = 0;
    for (int k = 0; k < NEXP; k++) if (r >= soff[k + 1]) e = k + 1;
    if (e > NEXP - 1) e = NEXP - 1;
    blk_e[tid] = e;
  }
}

// ---------- assign: token-slot -> sorted row; per-row weight ----------
__global__ void assign_k(const int* topi, const float* topw, int* cursor,
                         int* rowtok, float* rww) {
  int i = blockIdx.x * 256 + threadIdx.x;  // i < 8192
  int e = topi[i]; if (e < 0) e = 0; if (e >= NEXP) e = NEXP - 1;
  int r = atomicAdd(&cursor[e], 1);
  if (r < 0) r = 0; if (r >= CAP_ROWS) r = CAP_ROWS - 1;
  rowtok[r] = i >> 1;
  rww[r] = topw[i];
}

// ---------- transpose+convert: f32 [R][C] -> bf16 [C][R], batched ----------
__global__ void transpose_cvt_k(const float* __restrict__ src, u16* __restrict__ dst,
                                int R, int C) {
  __shared__ float tile[32][33];
  size_t base = (size_t)blockIdx.z * R * C;
  int c0 = blockIdx.x * 32, r0 = blockIdx.y * 32;
#pragma unroll
  for (int i = 0; i < 4; i++)
    tile[threadIdx.y + i * 8][threadIdx.x] =
        src[base + (size_t)(r0 + threadIdx.y + i * 8) * C + c0 + threadIdx.x];
  __syncthreads();
#pragma unroll
  for (int i = 0; i < 4; i++)
    dst[base + (size_t)(c0 + threadIdx.y + i * 8) * R + r0 + threadIdx.x] =
        f2b(tile[threadIdx.x][threadIdx.y + i * 8]);
}

// ---------- 128x128 bf16 MFMA GEMM, B pre-transposed [N][K] ----------
// MODE 0: gelu -> bf16 store to C16
// MODE 1: f32 store to Cf
// MODE 2: atomic f32: Cf[rowtok[row]*N+col] += rww[row]*v  (skip rowtok<0)
// gatherA: A-row indirection for staging (fused token gather), -1 -> 0.
template <int MODE>
__global__ __launch_bounds__(256) void gemm_bt(
    const u16* __restrict__ A, const u16* __restrict__ Bt,
    u16* __restrict__ C16, float* __restrict__ Cf,
    int N, int K, const int* __restrict__ blk_e, const int* __restrict__ nrows,
    size_t bstride, const int* __restrict__ gatherA,
    const int* __restrict__ rowtok, const float* __restrict__ rww) {
  const int m0 = blockIdx.y * 128, n0 = blockIdx.x * 128;
  if (nrows && m0 >= *nrows) return;
  if (blk_e) Bt += (size_t)blk_e[blockIdx.y] * bstride;

  __shared__ u16 As[128 * 32];
  __shared__ u16 Bs[128 * 32];
  const int tid = threadIdx.x, wave = tid >> 6, lane = tid & 63;
  // staging: wave w covers rows [w*16, w*16+16), 16B/lane; LDS = base + lane*16
  const int srow = wave * 16 + (lane >> 2);
  const int scol = (lane & 3) * 8;
  int r0 = m0 + srow, r1 = r0 + 64;
  if (gatherA) {
    int t = gatherA[r0]; r0 = (t < 0 || t >= T_TOK) ? 0 : t;
    t = gatherA[r1];     r1 = (t < 0 || t >= T_TOK) ? 0 : t;
  }
  const u16* Ag0 = A + (size_t)r0 * K + scol;
  const u16* Ag1 = A + (size_t)r1 * K + scol;
  const u16* Bg = Bt + (size_t)(n0 + srow) * K + scol;
  u16* Al = As + srow * 32 + scol;
  u16* Bl = Bs + srow * 32 + scol;

  const int wr = (wave >> 1) * 64, wc = (wave & 1) * 64;
  const int fr = lane & 15, fk = (lane >> 4) * 8;

  floatx4 acc[4][4];
#pragma unroll
  for (int mi = 0; mi < 4; mi++)
#pragma unroll
    for (int ni = 0; ni < 4; ni++) acc[mi][ni] = (floatx4){0.f, 0.f, 0.f, 0.f};

  for (int k0 = 0; k0 < K; k0 += 32) {
    __syncthreads();
    GLD16(Ag0 + k0, Al);
    GLD16(Ag1 + k0, Al + 64 * 32);
    GLD16(Bg + k0, Bl);
    GLD16(Bg + k0 + (size_t)64 * K, Bl + 64 * 32);
    __syncthreads();
    short8 aF[4], bF[4];
#pragma unroll
    for (int mi = 0; mi < 4; mi++)
      aF[mi] = *(const short8*)(As + (wr + mi * 16 + fr) * 32 + fk);
#pragma unroll
    for (int ni = 0; ni < 4; ni++)
      bF[ni] = *(const short8*)(Bs + (wc + ni * 16 + fr) * 32 + fk);
#pragma unroll
    for (int mi = 0; mi < 4; mi++)
#pragma unroll
      for (int ni = 0; ni < 4; ni++)
        acc[mi][ni] = __builtin_amdgcn_mfma_f32_16x16x32_bf16(aF[mi], bF[ni],
                                                              acc[mi][ni], 0, 0, 0);
  }
  // epilogue: C/D layout col=lane&15, row=(lane>>4)*4+reg
#pragma unroll
  for (int mi = 0; mi < 4; mi++)
#pragma unroll
    for (int r = 0; r < 4; r++) {
      int row = m0 + wr + mi * 16 + (lane >> 4) * 4 + r;
      int tok = 0; float w = 0.f;
      if (MODE == 2) {
        tok = rowtok[row];
        if (tok >= 0) w = rww[row];
      }
#pragma unroll
      for (int ni = 0; ni < 4; ni++) {
        int col = n0 + wc + ni * 16 + fr;
        float v = acc[mi][ni][r];
        if (MODE == 0) {
          v = 0.5f * v * (1.0f + erff(v * 0.70710678118654752f));
          C16[(size_t)row * N + col] = f2b(v);
        } else if (MODE == 1) {
          Cf[(size_t)row * N + col] = v;
        } else {
          if (tok >= 0) atomicAdd(Cf + (size_t)tok * N + col, w * v);
        }
      }
    }
}

extern "C" void kernel_launch(void* const* d_in, const int* in_sizes, int n_in,
                              void* d_out, int out_size, void* d_ws, size_t ws_size,
                              hipStream_t stream) {
  const float* x  = (const float*)d_in[0];
  const float* Wg = (const float*)d_in[1];
  const float* Wu = (const float*)d_in[2];
  const float* Wd = (const float*)d_in[3];
  const float* W1 = (const float*)d_in[4];
  const float* W2 = (const float*)d_in[5];
  float* out = (float*)d_out;

  // ---- workspace layout (phase-reused; ~102 MB) ----
  char* ws = (char*)d_ws;
  size_t off = 0;
  auto alloc = [&](size_t b) -> void* {
    void* p = ws + off; off += (b + 255) & ~(size_t)255; return p;
  };
  int*   counts = (int*)alloc(NEXP * 4);
  int*   cursor = (int*)alloc(NEXP * 4);
  int*   nrows  = (int*)alloc(4);
  int*   blk_e  = (int*)alloc(128 * 4);
  int*   topi   = (int*)alloc(T_TOK * 2 * 4);
  float* topw   = (float*)alloc(T_TOK * 2 * 4);
  int*   rowtok = (int*)alloc(CAP_ROWS * 4);
  float* rww    = (float*)alloc(CAP_ROWS * 4);
  u16*   Xb     = (u16*)alloc((size_t)T_TOK * DDIM * 2);            // 8.4 MB
  u16*   WtA    = (u16*)alloc((size_t)DDIM * FDIM * 2);             // 4.2 MB: W1t then W2t
  u16*   WtB    = (u16*)alloc((size_t)NEXP * FDIM * DDIM * 2);      // 33.6 MB: Wut then Wdt
  u16*   H1g    = (u16*)alloc((size_t)T_TOK * FDIM * 2);            // 16.8 MB
  u16*   Hrg    = (u16*)alloc((size_t)CAP_ROWS * FDIM * 2);         // 37.7 MB
  (void)n_in; (void)in_sizes; (void)out_size;

  // ---- ws guard: sentinel output so this failure mode is identifiable ----
  if (ws_size < off) {
    fallback_k<<<(T_TOK * DDIM + 255) / 256, 256, 0, stream>>>(out, T_TOK * DDIM);
    return;
  }

  u16* W1t = WtA;  u16* Wut = WtB;   // phase-1 views
  u16* W2t = WtA;  u16* Wdt = WtB;   // phase-2/3 views

  dim3 tb(32, 8);
  // ---- routing (f32 logits: selection must match reference) ----
  init_k<<<(CAP_ROWS + 255) / 256, 256, 0, stream>>>(counts, rowtok);
  cvt_k<<<T_TOK * DDIM / 1024, 256, 0, stream>>>(x, Xb);
  router_k<<<T_TOK / 16, 256, 0, stream>>>(x, Wg, topi, topw, counts);
  scan_k<<<1, 128, 0, stream>>>(counts, cursor, blk_e, nrows);
  assign_k<<<T_TOK * 2 / 256, 256, 0, stream>>>(topi, topw, cursor, rowtok, rww);
  // ---- phase 1: up-projections ----
  transpose_cvt_k<<<dim3(FDIM / 32, DDIM / 32, 1), tb, 0, stream>>>(W1, W1t, DDIM, FDIM);
  transpose_cvt_k<<<dim3(FDIM / 32, DDIM / 32, NEXP), tb, 0, stream>>>(Wu, Wut, DDIM, FDIM);
  // H1g = gelu(x @ W1)   [4096,2048] bf16
  gemm_bt<0><<<dim3(FDIM / 128, T_TOK / 128), 256, 0, stream>>>(
      Xb, W1t, H1g, nullptr, FDIM, DDIM, nullptr, nullptr, 0, nullptr, nullptr, nullptr);
  // Hrg = gelu(gather(x) @ Wu[e])  [<=9216,2048] bf16 (fused token gather)
  gemm_bt<0><<<dim3(FDIM / 128, CAP_MBLK), 256, 0, stream>>>(
      Xb, Wut, Hrg, nullptr, FDIM, DDIM, blk_e, nrows, (size_t)FDIM * DDIM,
      rowtok, nullptr, nullptr);
  // ---- phase 2: shared down -> out (f32, full overwrite) ----
  transpose_cvt_k<<<dim3(DDIM / 32, FDIM / 32, 1), tb, 0, stream>>>(W2, W2t, FDIM, DDIM);
  gemm_bt<1><<<dim3(DDIM / 128, T_TOK / 128), 256, 0, stream>>>(
      H1g, W2t, nullptr, out, DDIM, FDIM, nullptr, nullptr, 0, nullptr, nullptr, nullptr);
  // ---- phase 3: routed down, combine fused via atomicAdd into out ----
  transpose_cvt_k<<<dim3(DDIM / 32, FDIM / 32, NEXP), tb, 0, stream>>>(Wd, Wdt, FDIM, DDIM);
  gemm_bt<2><<<dim3(DDIM / 128, CAP_MBLK), 256, 0, stream>>>(
      Hrg, Wdt, nullptr, out, DDIM, FDIM, blk_e, nrows, (size_t)DDIM * FDIM,
      nullptr, rowtok, rww);
}